// Round 8
// baseline (2636.235 us; speedup 1.0000x reference)
//
#include <hip/hip_runtime.h>
#include <hip/hip_fp16.h>
#include <stdint.h>

#define Tdim 1024
#define INdim 256
#define Hdim 256
#define COLS 1024
#define NSLICE 8
#define NGRP 8
#define GB 16          // batches per group (MFMA M)
#define UPB 32         // units per slice
#define CPB 128        // cols per block
#define NTHREADS 512
#define FLAG_STRIDE ((Tdim + 1) * NSLICE)
#define FLAG_BYTES (NGRP * FLAG_STRIDE * 4)   // 262,400 (memset region)
#define HBUF_OFF 266240                        // hbuf: [2][NGRP][GB][Hdim] f16 = 131,072 B

typedef _Float16 half8 __attribute__((ext_vector_type(8)));
typedef float f32x4 __attribute__((ext_vector_type(4)));

__device__ __forceinline__ uint16_t f2h(float f) {
    __half h = __float2half(f);
    return *reinterpret_cast<uint16_t*>(&h);
}
__device__ __forceinline__ uint32_t pk2(float lo, float hi) {
    return (uint32_t)f2h(lo) | ((uint32_t)f2h(hi) << 16);
}
__device__ __forceinline__ float sigm(float v) {
    return __builtin_amdgcn_rcpf(1.f + __expf(-v));
}
__device__ __forceinline__ float tanhfast(float v) {
    float e = __expf(2.f * v);
    return 1.f - 2.f * __builtin_amdgcn_rcpf(e + 1.f);
}
__device__ __forceinline__ size_t hb_idx(int par, int grp, int m, int u) {
    return ((((size_t)par * NGRP + grp) * GB + m) << 8) | (size_t)u;
}

// MFMA 16x16x32 f16 lane roles (verified r4-r6):
//   A: lane l -> row(m) = l&15, k = (l>>4)*8 + e
//   B: lane l -> col    = l&15 (per-lane W regs), k = (l>>4)*8 + e
//   C/D: lane l, reg r -> row(m) = (l>>4)*4 + r, col = l&15
__global__ __launch_bounds__(NTHREADS, 1) void lstm_main(
    const float* __restrict__ x, const float* __restrict__ h0,
    const float* __restrict__ c0, const float* __restrict__ wx,
    const float* __restrict__ wh, const float* __restrict__ bias,
    float* __restrict__ out, uint32_t* flags, uint16_t* hbuf)
{
    const int tid   = threadIdx.x;
    const int grp   = blockIdx.x & 7;
    const int slice = blockIdx.x >> 3;
    const int lane  = tid & 63;
    const int wave  = tid >> 6;
    const int cw    = lane & 15;
    const int lhi   = lane >> 4;          // 0..3
    const int cl    = wave * 16 + cw;     // block-local col: (u_local<<2)|g
    const int g     = cl & 3;
    const int ul    = cl >> 2;            // 0..31
    const int u     = slice * UPB + ul;
    const int gcol  = g * Hdim + u;

    __shared__ __align__(16) uint16_t Wl[CPB * 512];     // 128 KB (prologue only)
    __shared__ __align__(16) uint16_t X[2][GB][32][8];   // 16 KB, m-major, slot=ko^(m&7)
    __shared__ __align__(16) uint16_t Hs[GB][32][8];     // 8 KB, same swizzle
    __shared__ __align__(16) uint16_t Hp16[GB][UPB];     // 1 KB   publish staging (f16)
    __shared__ __align__(16) float    Hpf[GB][UPB + 4];  // 2.25 KB fullh staging (padded)

    // ---------- prologue ----------
    for (int idx = tid; idx < CPB * 512; idx += NTHREADS) {
        int k  = idx >> 7;
        int ci = idx & 127;
        int uu = ci & 31, gg = ci >> 5;
        int cg = gg * Hdim + slice * UPB + uu;          // global col (coalesced over uu)
        int c  = (uu << 2) | gg;                        // block-local col
        float w = (k < INdim) ? wx[(size_t)k * COLS + cg]
                              : wh[(size_t)(k - INdim) * COLS + cg];
        int e = c * 512 + ((((k >> 3) ^ (c & 7)) << 3) | (k & 7));
        Wl[e] = f2h(w);
    }
    const int m_s   = tid >> 5;           // staging row (batch)
    const int ko_s  = tid & 31;           // staging k-oct
    const int slt_s = ko_s ^ (m_s & 7);   // swizzled slot for staging writes
    {   // stage x_0 directly (conflict-free b128 write)
        const float4* xs = reinterpret_cast<const float4*>(
            &x[((size_t)(grp * GB + m_s) * Tdim + 0) * INdim + ko_s * 8]);
        float4 a = xs[0], b = xs[1];
        uint4 pkv = {pk2(a.x, a.y), pk2(a.z, a.w), pk2(b.x, b.y), pk2(b.z, b.w)};
        *reinterpret_cast<uint4*>(&X[0][m_s][slt_s][0]) = pkv;
    }
    // prefetch x_1 into regs
    float4 xp0, xp1;
    {
        const float4* xs = reinterpret_cast<const float4*>(
            &x[((size_t)(grp * GB + m_s) * Tdim + 1) * INdim + ko_s * 8]);
        xp0 = xs[0]; xp1 = xs[1];
    }
    if (tid < 64) {  // h0 -> hbuf[0] (own slice's units)
        int m = tid >> 2, uo = tid & 3;
        int u0 = slice * UPB + uo * 8;
        const float4* hs = reinterpret_cast<const float4*>(
            &h0[(size_t)(grp * GB + m) * Hdim + u0]);
        float4 a = hs[0], b = hs[1];
        unsigned long long p0 =
            (unsigned long long)pk2(a.x, a.y) | ((unsigned long long)pk2(a.z, a.w) << 32);
        unsigned long long p1 =
            (unsigned long long)pk2(b.x, b.y) | ((unsigned long long)pk2(b.z, b.w) << 32);
        unsigned long long* hp =
            reinterpret_cast<unsigned long long*>(&hbuf[hb_idx(0, grp, m, u0)]);
        __hip_atomic_exchange(&hp[0], p0, __ATOMIC_RELAXED, __HIP_MEMORY_SCOPE_AGENT);
        __hip_atomic_exchange(&hp[1], p1, __ATOMIC_RELAXED, __HIP_MEMORY_SCOPE_AGENT);
    }
    float c_reg[4];
    #pragma unroll
    for (int r = 0; r < 4; ++r)
        c_reg[r] = c0[(size_t)(grp * GB + lhi * 4 + r) * Hdim + u];
    const float bv = bias[gcol];
    asm volatile("s_waitcnt vmcnt(0)" ::: "memory");   // hbuf init serviced at MALL
    __syncthreads();
    uint32_t* fl = flags + grp * FLAG_STRIDE;
    if (tid == 0)
        __hip_atomic_exchange(&fl[slice], 1u, __ATOMIC_RELAXED, __HIP_MEMORY_SCOPE_AGENT);

    // W fragments -> registers (one-time; Wl dead afterwards)
    const uint32_t swz = (uint32_t)(cl & 7);
    const uint16_t* wrow = &Wl[cl * 512];
    half8 Wf[16];
    #pragma unroll
    for (int i = 0; i < 16; ++i)
        Wf[i] = *reinterpret_cast<const half8*>(&wrow[(((uint32_t)(i * 4 + lhi)) ^ swz) << 3]);

    const int swz_a = cw & 7;             // A-read slot xor (row = cw)
    float hv[4] = {0.f, 0.f, 0.f, 0.f};

    // ---------- time loop ----------
    for (int t = 0; t < Tdim; ++t) {
        const int par = t & 1, pn = par ^ 1;

        // stage x_{t+1} from regs (loaded last iteration; single b128, conflict-free)
        {
            uint4 pkv = {pk2(xp0.x, xp0.y), pk2(xp0.z, xp0.w),
                         pk2(xp1.x, xp1.y), pk2(xp1.z, xp1.w)};
            *reinterpret_cast<uint4*>(&X[pn][m_s][slt_s][0]) = pkv;
        }
        // issue prefetch of x_{t+2}
        {
            int tn = (t + 2 < Tdim) ? t + 2 : Tdim - 1;
            const float4* xs = reinterpret_cast<const float4*>(
                &x[((size_t)(grp * GB + m_s) * Tdim + tn) * INdim + ko_s * 8]);
            xp0 = xs[0]; xp1 = xs[1];
        }

        // x-part GEMM (k 0..255) — independent of h(t)
        f32x4 acc0 = {0.f, 0.f, 0.f, 0.f}, acc1 = {0.f, 0.f, 0.f, 0.f};
        #pragma unroll
        for (int s = 0; s < 8; s += 2) {
            int ko0 = s * 4 + lhi, ko1 = ko0 + 4;
            half8 a0 = *reinterpret_cast<const half8*>(&X[par][cw][ko0 ^ swz_a][0]);
            acc0 = __builtin_amdgcn_mfma_f32_16x16x32_f16(a0, Wf[s], acc0, 0, 0, 0);
            half8 a1 = *reinterpret_cast<const half8*>(&X[par][cw][ko1 ^ swz_a][0]);
            acc1 = __builtin_amdgcn_mfma_f32_16x16x32_f16(a1, Wf[s + 1], acc1, 0, 0, 0);
        }

        // wait for h(t) from all 8 slices — relaxed atomic polls (MALL-serviced)
        if (tid < NSLICE) {
            while (__hip_atomic_load(&fl[t * NSLICE + tid], __ATOMIC_RELAXED,
                                     __HIP_MEMORY_SCOPE_AGENT) == 0) {}
        }
        __syncthreads();

        // stage h -> Hs (relaxed coherence-point loads, one b128 LDS write)
        {
            const unsigned long long* hp = reinterpret_cast<const unsigned long long*>(
                &hbuf[hb_idx(par, grp, m_s, ko_s * 8)]);
            unsigned long long h0v = __hip_atomic_load(&hp[0], __ATOMIC_RELAXED,
                                                       __HIP_MEMORY_SCOPE_AGENT);
            unsigned long long h1v = __hip_atomic_load(&hp[1], __ATOMIC_RELAXED,
                                                       __HIP_MEMORY_SCOPE_AGENT);
            uint4 hw = {(uint32_t)h0v, (uint32_t)(h0v >> 32),
                        (uint32_t)h1v, (uint32_t)(h1v >> 32)};
            *reinterpret_cast<uint4*>(&Hs[m_s][slt_s][0]) = hw;
        }
        __syncthreads();

        // h-part GEMM (k 256..511)
        #pragma unroll
        for (int s = 0; s < 8; s += 2) {
            int ko0 = s * 4 + lhi, ko1 = ko0 + 4;
            half8 a0 = *reinterpret_cast<const half8*>(&Hs[cw][ko0 ^ swz_a][0]);
            acc0 = __builtin_amdgcn_mfma_f32_16x16x32_f16(a0, Wf[8 + s], acc0, 0, 0, 0);
            half8 a1 = *reinterpret_cast<const half8*>(&Hs[cw][ko1 ^ swz_a][0]);
            acc1 = __builtin_amdgcn_mfma_f32_16x16x32_f16(a1, Wf[9 + s], acc1, 0, 0, 0);
        }

        // gates + state update (4 rows per lane)
        #pragma unroll
        for (int r = 0; r < 4; ++r) {
            float tval = acc0[r] + acc1[r] + bv;
            float act = (g == 3) ? tanhfast(tval) : sigm(tval);
            float x1  = __shfl_xor(act, 1);
            float e0  = (g & 1) ? x1 : act;
            float o1  = (g & 1) ? act : x1;
            float e0s = __shfl_xor(e0, 2);
            float o1s = __shfl_xor(o1, 2);
            float f_ = (g < 2) ? e0  : e0s;
            float i_ = (g < 2) ? o1  : o1s;
            float o_ = (g < 2) ? e0s : e0;
            float g_ = (g < 2) ? o1s : o1;
            c_reg[r] = fmaf(c_reg[r], f_, g_ * i_);
            hv[r] = tanhfast(c_reg[r]) * o_;
        }

        // drop h into LDS staging tiles
        if (g == 0) {
            #pragma unroll
            for (int r = 0; r < 4; ++r) {
                int m = lhi * 4 + r;
                Hp16[m][ul] = f2h(hv[r]);
                Hpf[m][ul]  = hv[r];
            }
        }
        __syncthreads();

        // publish: 128 coalesced 8B atomic-RMW (serviced & retained at MALL)
        if (tid < 128) {
            int m = tid >> 3, q = tid & 7;
            unsigned long long v =
                *reinterpret_cast<const unsigned long long*>(&Hp16[m][q * 4]);
            __hip_atomic_exchange(reinterpret_cast<unsigned long long*>(
                                      &hbuf[hb_idx(pn, grp, m, slice * UPB + q * 4)]),
                                  v, __ATOMIC_RELAXED, __HIP_MEMORY_SCOPE_AGENT);
        }
        asm volatile("s_waitcnt vmcnt(0)" ::: "memory");   // publish RMWs completed
        __syncthreads();
        if (tid == 0)
            __hip_atomic_exchange(&fl[(t + 1) * NSLICE + slice], 1u,
                                  __ATOMIC_RELAXED, __HIP_MEMORY_SCOPE_AGENT);

        // fullh stores — after the flag, off the critical path (waves 2-3)
        if (tid >= 128 && tid < 256) {
            int j = tid - 128;
            int m = j >> 3, q = j & 7;
            float4 v = *reinterpret_cast<const float4*>(&Hpf[m][q * 4]);
            *reinterpret_cast<float4*>(
                &out[((size_t)(grp * GB + m) * Tdim + t) * Hdim + slice * UPB + q * 4]) = v;
        }
    }

    // final h_f, c_f
    if (g == 0) {
        const size_t fsz = (size_t)(NGRP * GB) * Tdim * Hdim;
        #pragma unroll
        for (int r = 0; r < 4; ++r) {
            int m = lhi * 4 + r;
            out[fsz + (size_t)(grp * GB + m) * Hdim + u] = hv[r];
            out[fsz + (size_t)(NGRP * GB) * Hdim + (size_t)(grp * GB + m) * Hdim + u] = c_reg[r];
        }
    }
}

extern "C" void kernel_launch(void* const* d_in, const int* in_sizes, int n_in,
                              void* d_out, int out_size, void* d_ws, size_t ws_size,
                              hipStream_t stream) {
    const float* x    = (const float*)d_in[0];
    const float* h0   = (const float*)d_in[1];
    const float* c0   = (const float*)d_in[2];
    const float* wx   = (const float*)d_in[3];
    const float* wh   = (const float*)d_in[4];
    const float* bias = (const float*)d_in[5];
    float* out = (float*)d_out;
    uint32_t* flags = (uint32_t*)d_ws;
    uint16_t* hbuf  = (uint16_t*)((char*)d_ws + HBUF_OFF);

    hipMemsetAsync(flags, 0, FLAG_BYTES, stream);

    void* args[] = {(void*)&x, (void*)&h0, (void*)&c0, (void*)&wx, (void*)&wh,
                    (void*)&bias, (void*)&out, (void*)&flags, (void*)&hbuf};
    hipLaunchCooperativeKernel((const void*)lstm_main, dim3(NSLICE * NGRP),
                               dim3(NTHREADS), args, 0, stream);
}